// Round 1
// baseline (330.196 us; speedup 1.0000x reference)
//
#include <hip/hip_runtime.h>

#define IMG_H 1024
#define IMG_W 1024
#define RPB   8       // output rows per block
#define TPB   256     // each thread owns 4 columns; each wave owns 256 contiguous cols

struct HS { float x[4], y[4], xx[4], yy[4], xy[4]; };

__device__ __forceinline__ void zero_hs(HS& h)
{
#pragma unroll
    for (int j = 0; j < 4; ++j) { h.x[j]=0.f; h.y[j]=0.f; h.xx[j]=0.f; h.yy[j]=0.f; h.xy[j]=0.f; }
}

// Horizontal 3-sums from 6 inputs (halo scalars already masked by caller).
__device__ __forceinline__ void hsum6(float xl, float4 xv, float xr6,
                                      float yl, float4 yv, float yr6, HS& h)
{
    float xs[6] = { xl, xv.x, xv.y, xv.z, xv.w, xr6 };
    float ys[6] = { yl, yv.x, yv.y, yv.z, yv.w, yr6 };

    float pxx[6], pyy[6], pxy[6];
#pragma unroll
    for (int k = 0; k < 6; ++k) {
        pxx[k] = xs[k] * xs[k];
        pyy[k] = ys[k] * ys[k];
        pxy[k] = xs[k] * ys[k];
    }
#pragma unroll
    for (int j = 0; j < 4; ++j) {
        h.x[j]  = xs[j]  + xs[j + 1]  + xs[j + 2];
        h.y[j]  = ys[j]  + ys[j + 1]  + ys[j + 2];
        h.xx[j] = pxx[j] + pxx[j + 1] + pxx[j + 2];
        h.yy[j] = pyy[j] + pyy[j + 1] + pyy[j + 2];
        h.xy[j] = pxy[j] + pxy[j + 1] + pxy[j + 2];
    }
}

// Scaled SSIM (both num/den factors x81, EPS x6561; absmax==0 since R2):
//   num = (2*sx*sy + 81*C1) * (18*sxy - 2*sx*sy + 81*C2)
//   den = (sx^2+sy^2 + 81*C1) * (9*(sxx+syy) - (sx^2+sy^2) + 81*C2) + 6561*EPS
__device__ __forceinline__ void accum(const HS& A, const HS& B, const HS& C, float& acc)
{
    const float c1s  = 81.0f * 1e-4f;
    const float c2s  = 81.0f * 9e-4f;
    const float epss = 6561.0f * 1e-8f;
#pragma unroll
    for (int j = 0; j < 4; ++j) {
        const float sx  = A.x[j]  + B.x[j]  + C.x[j];
        const float sy  = A.y[j]  + B.y[j]  + C.y[j];
        const float sxx = A.xx[j] + B.xx[j] + C.xx[j];
        const float syy = A.yy[j] + B.yy[j] + C.yy[j];
        const float sxy = A.xy[j] + B.xy[j] + C.xy[j];

        const float t1 = sx * sy;
        const float t2 = fmaf(sx, sx, sy * sy);
        const float s2 = sxx + syy;
        const float An = fmaf(2.0f, t1, c1s);
        const float Bn = fmaf(-2.0f, t1, fmaf(18.0f, sxy, c2s));
        const float Xd = t2 + c1s;
        const float Yd = fmaf(9.0f, s2, c2s - t2);
        const float den = fmaf(Xd, Yd, epss);
        const float num = An * Bn;
        acc = fmaf(num, __builtin_amdgcn_rcpf(den), acc);
    }
}

// R7: halo values come from __shfl of the already-prefetched float4s (DS pipe,
// no vmcnt on the consume path). Only lanes 0/63 touch memory for halos (2-lane
// predicated loads), and those are issued in the PREFETCH stage (one step of
// slack) exactly like the float4s. This removes the 4 per-thread same-step
// scalar gathers (~17 cache lines each in the TA/L1 pipe + exposed L1/L2
// latency every step) that kept VALUBusy at 36%.
__global__ __launch_bounds__(TPB, 4)
void ssim_map_sum_kernel(const float* __restrict__ x,
                         const float* __restrict__ y,
                         float* __restrict__ part)
{
    const int rb = blockIdx.x;
    const int n  = blockIdx.y;
    const int r0 = rb * RPB;
    const int tid = (int)threadIdx.x;
    const int c  = tid * 4;
    const int lane = tid & 63;
    const bool eL = (lane == 0);
    const bool eR = (lane == 63);
    const bool edge = eL | eR;

    const int   cl = (c > 0) ? c - 1 : 0;
    const int   cr = (c + 4 < IMG_W) ? c + 4 : IMG_W - 1;
    const int   hc = eL ? cl : cr;            // the one halo column an edge lane loads
    const float lm = (c > 0) ? 1.0f : 0.0f;
    const float rm = (c + 4 < IMG_W) ? 1.0f : 0.0f;
    const float hm = eL ? lm : rm;            // mask for the edge-override value

    const float* xi = x + (size_t)n * IMG_H * IMG_W;
    const float* yi = y + (size_t)n * IMG_H * IMG_W;

    // Interior lanes: xl = lane-1's xv.w, xr6 = lane+1's xv.x (same wave).
    // Edge lanes (wave boundary / image boundary) override with the loaded
    // halo scalar, pre-masked. Values are bit-identical to the R6 gathers.
#define CONSUME(XV, YV, HX, HY, H)                                             \
    {                                                                          \
        float xl_ = __shfl_up((XV).w, 1);                                      \
        float yl_ = __shfl_up((YV).w, 1);                                      \
        float xr_ = __shfl_down((XV).x, 1);                                    \
        float yr_ = __shfl_down((YV).x, 1);                                    \
        if (eL) { xl_ = (HX) * hm; yl_ = (HY) * hm; }                          \
        if (eR) { xr_ = (HX) * hm; yr_ = (HY) * hm; }                          \
        hsum6(xl_, (XV), xr_, yl_, (YV), yr_, H);                              \
    }

    HS hA, hB, hC;

    // ---- Prologue: hA = row r0-1 (or zero), hB = row r0 (immediate loads;
    // latency amortized across 16 blocks/CU).
    if (r0 > 0) {
        const float* xr = xi + (size_t)(r0 - 1) * IMG_W;
        const float* yr = yi + (size_t)(r0 - 1) * IMG_W;
        float4 xv = *reinterpret_cast<const float4*>(xr + c);
        float4 yv = *reinterpret_cast<const float4*>(yr + c);
        float hx = 0.f, hy = 0.f;
        if (edge) { hx = xr[hc]; hy = yr[hc]; }
        CONSUME(xv, yv, hx, hy, hA);
    } else {
        zero_hs(hA);
    }
    {
        const float* xr = xi + (size_t)r0 * IMG_W;
        const float* yr = yi + (size_t)r0 * IMG_W;
        float4 xv = *reinterpret_cast<const float4*>(xr + c);
        float4 yv = *reinterpret_cast<const float4*>(yr + c);
        float hx = 0.f, hy = 0.f;
        if (edge) { hx = xr[hc]; hy = yr[hc]; }
        CONSUME(xv, yv, hx, hy, hB);
    }

    // Prefetch row r0+1 (always in-bounds: r0 <= IMG_H-RPB): float4s + edge halos.
    float4 pxa, pya, pxb, pyb;
    float  hxa = 0.f, hya = 0.f, hxb = 0.f, hyb = 0.f;
    {
        const float* xr = xi + (size_t)(r0 + 1) * IMG_W;
        const float* yr = yi + (size_t)(r0 + 1) * IMG_W;
        pxa = *reinterpret_cast<const float4*>(xr + c);
        pya = *reinterpret_cast<const float4*>(yr + c);
        if (edge) { hxa = xr[hc]; hya = yr[hc]; }
    }

    float acc = 0.0f;

    // Step k (output row r0+k): FIRST issue prefetch of row r0+k+2 (float4s AND
    // edge halo scalars) into the other buffer — full step of slack before its
    // wait — THEN consume the buffered row r0+k+1 entirely from registers.
#define STEP_MAIN(k, PXI, PYI, HXI, HYI, PXO, PYO, HXO, HYO, P, Q, R)              \
    {                                                                              \
        const float* xw = xi + (size_t)(r0 + (k) + 2) * IMG_W;                     \
        const float* yw = yi + (size_t)(r0 + (k) + 2) * IMG_W;                     \
        PXO = *reinterpret_cast<const float4*>(xw + c);                            \
        PYO = *reinterpret_cast<const float4*>(yw + c);                            \
        HXO = 0.f; HYO = 0.f;                                                      \
        if (edge) { HXO = xw[hc]; HYO = yw[hc]; }                                  \
        CONSUME(PXI, PYI, HXI, HYI, R);                                            \
        accum(P, Q, R, acc);                                                       \
    }

    // k = 0..5: prefetched rows r0+2 .. r0+7 all in-bounds (r0+RPB-1 max).
    STEP_MAIN(0, pxa, pya, hxa, hya, pxb, pyb, hxb, hyb, hA, hB, hC)
    STEP_MAIN(1, pxb, pyb, hxb, hyb, pxa, pya, hxa, hya, hB, hC, hA)
    STEP_MAIN(2, pxa, pya, hxa, hya, pxb, pyb, hxb, hyb, hC, hA, hB)
    STEP_MAIN(3, pxb, pyb, hxb, hyb, pxa, pya, hxa, hya, hA, hB, hC)
    STEP_MAIN(4, pxa, pya, hxa, hya, pxb, pyb, hxb, hyb, hB, hC, hA)
    STEP_MAIN(5, pxb, pyb, hxb, hyb, pxa, pya, hxa, hya, hC, hA, hB)
#undef STEP_MAIN

    // k = 6: prefetch row r0+8 with CLAMPED row index (OOB only for the last
    // block-row; masked at consume). Consume row r0+7 (in-bounds) normally.
    {
        const int rr = (r0 + 8 < IMG_H) ? r0 + 8 : IMG_H - 1;
        const float* xw = xi + (size_t)rr * IMG_W;
        const float* yw = yi + (size_t)rr * IMG_W;
        pxb = *reinterpret_cast<const float4*>(xw + c);
        pyb = *reinterpret_cast<const float4*>(yw + c);
        hxb = 0.f; hyb = 0.f;
        if (edge) { hxb = xw[hc]; hyb = yw[hc]; }
        CONSUME(pxa, pya, hxa, hya, hC);     // output row r0+6
        accum(hA, hB, hC, acc);
    }

    // k = 7 (final output row r0+7): consume row r0+8, row-masked. Masking the
    // float4 BEFORE the shuffles masks the shuffled neighbors too (rwm is
    // wave-uniform); the edge override gets an explicit *rwm.
    {
        const float rwm = (r0 + 8 < IMG_H) ? 1.0f : 0.0f;
        float4 xv = pxb, yv = pyb;
        xv.x *= rwm; xv.y *= rwm; xv.z *= rwm; xv.w *= rwm;
        yv.x *= rwm; yv.y *= rwm; yv.z *= rwm; yv.w *= rwm;
        const float hx = hxb * rwm, hy = hyb * rwm;
        CONSUME(xv, yv, hx, hy, hA);
        accum(hB, hC, hA, acc);
    }
#undef CONSUME

    // ---- Reduction: wave shuffle -> LDS -> ONE STORE per block (no global
    // atomic: 4096 single-address atomics serialized ~20cyc each in R1-R6).
#pragma unroll
    for (int off = 32; off > 0; off >>= 1)
        acc += __shfl_down(acc, off);

    __shared__ float red[TPB / 64];
    const int wave = tid >> 6;
    if (lane == 0) red[wave] = acc;
    __syncthreads();
    if (tid == 0) {
        float s = 0.0f;
#pragma unroll
        for (int w = 0; w < TPB / 64; ++w) s += red[w];
        part[blockIdx.y * gridDim.x + blockIdx.x] = s;
    }
}

__global__ __launch_bounds__(256)
void ssim_finalize_kernel(const float* __restrict__ part, int nparts,
                          float* __restrict__ out, float inv_count)
{
    float s = 0.0f;
    for (int i = (int)threadIdx.x; i < nparts; i += 256)
        s += part[i];
#pragma unroll
    for (int off = 32; off > 0; off >>= 1)
        s += __shfl_down(s, off);

    __shared__ float red[4];
    const int lane = (int)threadIdx.x & 63;
    const int wave = (int)threadIdx.x >> 6;
    if (lane == 0) red[wave] = s;
    __syncthreads();
    if (threadIdx.x == 0) {
        float t = red[0] + red[1] + red[2] + red[3];
        out[0] = 1.0f - t * inv_count;
    }
}

extern "C" void kernel_launch(void* const* d_in, const int* in_sizes, int n_in,
                              void* d_out, int out_size, void* d_ws, size_t ws_size,
                              hipStream_t stream)
{
    const float* x = (const float*)d_in[0];
    const float* y = (const float*)d_in[1];
    float* out  = (float*)d_out;
    float* part = (float*)d_ws;   // 4096 floats = 16 KB << ws_size

    const long long total = (long long)in_sizes[0];       // 32*1024*1024
    const int N = (int)(total / ((long long)IMG_H * IMG_W));
    const int nparts = (IMG_H / RPB) * N;

    dim3 grid(IMG_H / RPB, N);
    ssim_map_sum_kernel<<<grid, TPB, 0, stream>>>(x, y, part);

    ssim_finalize_kernel<<<1, 256, 0, stream>>>(part, nparts, out, 1.0f / (float)total);
}

// Round 2
// 278.441 us; speedup vs baseline: 1.1859x; 1.1859x over previous
//
#include <hip/hip_runtime.h>

#define IMG_H 1024
#define IMG_W 1024
#define RPB   8       // output rows per block
#define TPB   256     // each thread owns 4 columns

struct HS { float x[4], y[4], xx[4], yy[4], xy[4]; };

__device__ __forceinline__ void zero_hs(HS& h)
{
#pragma unroll
    for (int j = 0; j < 4; ++j) { h.x[j]=0.f; h.y[j]=0.f; h.xx[j]=0.f; h.yy[j]=0.f; h.xy[j]=0.f; }
}

// Horizontal 3-sums from 6 inputs (halo scalars already masked by caller).
__device__ __forceinline__ void hsum6(float xl, float4 xv, float xr6,
                                      float yl, float4 yv, float yr6, HS& h)
{
    float xs[6] = { xl, xv.x, xv.y, xv.z, xv.w, xr6 };
    float ys[6] = { yl, yv.x, yv.y, yv.z, yv.w, yr6 };

    float pxx[6], pyy[6], pxy[6];
#pragma unroll
    for (int k = 0; k < 6; ++k) {
        pxx[k] = xs[k] * xs[k];
        pyy[k] = ys[k] * ys[k];
        pxy[k] = xs[k] * ys[k];
    }
#pragma unroll
    for (int j = 0; j < 4; ++j) {
        h.x[j]  = xs[j]  + xs[j + 1]  + xs[j + 2];
        h.y[j]  = ys[j]  + ys[j + 1]  + ys[j + 2];
        h.xx[j] = pxx[j] + pxx[j + 1] + pxx[j + 2];
        h.yy[j] = pyy[j] + pyy[j + 1] + pyy[j + 2];
        h.xy[j] = pxy[j] + pxy[j + 1] + pxy[j + 2];
    }
}

// Scaled SSIM (both num/den factors x81, EPS x6561; absmax==0 since R2):
//   num = (2*sx*sy + 81*C1) * (18*sxy - 2*sx*sy + 81*C2)
//   den = (sx^2+sy^2 + 81*C1) * (9*(sxx+syy) - (sx^2+sy^2) + 81*C2) + 6561*EPS
__device__ __forceinline__ void accum(const HS& A, const HS& B, const HS& C, float& acc)
{
    const float c1s  = 81.0f * 1e-4f;
    const float c2s  = 81.0f * 9e-4f;
    const float epss = 6561.0f * 1e-8f;
#pragma unroll
    for (int j = 0; j < 4; ++j) {
        const float sx  = A.x[j]  + B.x[j]  + C.x[j];
        const float sy  = A.y[j]  + B.y[j]  + C.y[j];
        const float sxx = A.xx[j] + B.xx[j] + C.xx[j];
        const float syy = A.yy[j] + B.yy[j] + C.yy[j];
        const float sxy = A.xy[j] + B.xy[j] + C.xy[j];

        const float t1 = sx * sy;
        const float t2 = fmaf(sx, sx, sy * sy);
        const float s2 = sxx + syy;
        const float An = fmaf(2.0f, t1, c1s);
        const float Bn = fmaf(-2.0f, t1, fmaf(18.0f, sxy, c2s));
        const float Xd = t2 + c1s;
        const float Yd = fmaf(9.0f, s2, c2s - t2);
        const float den = fmaf(Xd, Yd, epss);
        const float num = An * Bn;
        acc = fmaf(num, __builtin_amdgcn_rcpf(den), acc);
    }
}

// R8: R6 structure (shuffle-free, uniform control flow — R7's shuffle+divergent
// edge version spilled 184 MB to scratch and regressed 100->151us), with ONE
// change: the 4 halo scalar gathers are HOISTED into the prefetch stage,
// ping-ponged in 8 named floats like the float4s. In R6 they were issued and
// consumed in the same step (~200cy L1/L2 latency fully exposed, 8x per
// block); now every VMEM op on the consume path was issued one full step
// earlier. Same loads, same values, same summation order -> absmax 0.
__global__ __launch_bounds__(TPB, 4)
void ssim_map_sum_kernel(const float* __restrict__ x,
                         const float* __restrict__ y,
                         float* __restrict__ part)
{
    const int rb = blockIdx.x;
    const int n  = blockIdx.y;
    const int r0 = rb * RPB;
    const int c  = (int)threadIdx.x * 4;

    const int   cl = (c > 0) ? c - 1 : 0;
    const int   cr = (c + 4 < IMG_W) ? c + 4 : IMG_W - 1;
    const float lm = (c > 0) ? 1.0f : 0.0f;
    const float rm = (c + 4 < IMG_W) ? 1.0f : 0.0f;

    const float* xi = x + (size_t)n * IMG_H * IMG_W;
    const float* yi = y + (size_t)n * IMG_H * IMG_W;

    HS hA, hB, hC;

    // ---- Prologue: hA = row r0-1 (or zero), hB = row r0 (immediate loads;
    // latency amortized across many blocks/CU).
    if (r0 > 0) {
        const float* xr = xi + (size_t)(r0 - 1) * IMG_W;
        const float* yr = yi + (size_t)(r0 - 1) * IMG_W;
        hsum6(xr[cl] * lm, *reinterpret_cast<const float4*>(xr + c), xr[cr] * rm,
              yr[cl] * lm, *reinterpret_cast<const float4*>(yr + c), yr[cr] * rm, hA);
    } else {
        zero_hs(hA);
    }
    {
        const float* xr = xi + (size_t)r0 * IMG_W;
        const float* yr = yi + (size_t)r0 * IMG_W;
        hsum6(xr[cl] * lm, *reinterpret_cast<const float4*>(xr + c), xr[cr] * rm,
              yr[cl] * lm, *reinterpret_cast<const float4*>(yr + c), yr[cr] * rm, hB);
    }

    // Prefetch row r0+1 (always in-bounds: r0 <= IMG_H-RPB): float4s AND the
    // 4 halo scalars, double-buffered in named registers (a/b).
    float4 pxa, pya, pxb, pyb;
    float  xla, xra, yla, yra, xlb, xrb, ylb, yrb;
    {
        const float* xr = xi + (size_t)(r0 + 1) * IMG_W;
        const float* yr = yi + (size_t)(r0 + 1) * IMG_W;
        pxa = *reinterpret_cast<const float4*>(xr + c);
        pya = *reinterpret_cast<const float4*>(yr + c);
        xla = xr[cl]; xra = xr[cr];
        yla = yr[cl]; yra = yr[cr];
    }

    float acc = 0.0f;

    // Step k (output row r0+k): FIRST issue ALL loads of row r0+k+2 (float4s +
    // halo scalars) into the other buffer — a full step of slack before their
    // wait — THEN consume the fully-buffered row r0+k+1 from registers only.
#define STEP_MAIN(k, PXI, PYI, XLI, XRI, YLI, YRI, PXO, PYO, XLO, XRO, YLO, YRO, P, Q, R) \
    {                                                                              \
        const float* xw = xi + (size_t)(r0 + (k) + 2) * IMG_W;                     \
        const float* yw = yi + (size_t)(r0 + (k) + 2) * IMG_W;                     \
        PXO = *reinterpret_cast<const float4*>(xw + c);                            \
        PYO = *reinterpret_cast<const float4*>(yw + c);                            \
        XLO = xw[cl]; XRO = xw[cr];                                                \
        YLO = yw[cl]; YRO = yw[cr];                                                \
        hsum6(XLI * lm, PXI, XRI * rm, YLI * lm, PYI, YRI * rm, R);                \
        accum(P, Q, R, acc);                                                       \
    }

    // k = 0..5: prefetched rows r0+2 .. r0+7 all in-bounds (r0+RPB-1 max).
    STEP_MAIN(0, pxa, pya, xla, xra, yla, yra, pxb, pyb, xlb, xrb, ylb, yrb, hA, hB, hC)
    STEP_MAIN(1, pxb, pyb, xlb, xrb, ylb, yrb, pxa, pya, xla, xra, yla, yra, hB, hC, hA)
    STEP_MAIN(2, pxa, pya, xla, xra, yla, yra, pxb, pyb, xlb, xrb, ylb, yrb, hC, hA, hB)
    STEP_MAIN(3, pxb, pyb, xlb, xrb, ylb, yrb, pxa, pya, xla, xra, yla, yra, hA, hB, hC)
    STEP_MAIN(4, pxa, pya, xla, xra, yla, yra, pxb, pyb, xlb, xrb, ylb, yrb, hB, hC, hA)
    STEP_MAIN(5, pxb, pyb, xlb, xrb, ylb, yrb, pxa, pya, xla, xra, yla, yra, hC, hA, hB)
#undef STEP_MAIN

    // k = 6: prefetch row r0+8 with CLAMPED row index (OOB only for the last
    // block-row; masked at consume). Consume prefetched row r0+7 normally.
    {
        const int rr = (r0 + 8 < IMG_H) ? r0 + 8 : IMG_H - 1;
        const float* xw = xi + (size_t)rr * IMG_W;
        const float* yw = yi + (size_t)rr * IMG_W;
        pxb = *reinterpret_cast<const float4*>(xw + c);
        pyb = *reinterpret_cast<const float4*>(yw + c);
        xlb = xw[cl]; xrb = xw[cr];
        ylb = yw[cl]; yrb = yw[cr];
        hsum6(xla * lm, pxa, xra * rm, yla * lm, pya, yra * rm, hC);
        accum(hA, hB, hC, acc);              // output row r0+6
    }

    // k = 7 (final output row r0+7): consume row r0+8, row-masked (rwm=0 zeroes
    // the whole row's contribution for the last block-row; loads were clamped
    // so no OOB reads).
    {
        const float rwm = (r0 + 8 < IMG_H) ? 1.0f : 0.0f;
        float4 xv = pxb, yv = pyb;
        xv.x *= rwm; xv.y *= rwm; xv.z *= rwm; xv.w *= rwm;
        yv.x *= rwm; yv.y *= rwm; yv.z *= rwm; yv.w *= rwm;
        hsum6(xlb * (lm * rwm), xv, xrb * (rm * rwm),
              ylb * (lm * rwm), yv, yrb * (rm * rwm), hA);
        accum(hB, hC, hA, acc);
    }

    // ---- Reduction: wave shuffle -> LDS -> ONE STORE per block (no global
    // atomic: 4096 single-address atomics serialized ~20cyc each in R1-R6).
#pragma unroll
    for (int off = 32; off > 0; off >>= 1)
        acc += __shfl_down(acc, off);

    __shared__ float red[TPB / 64];
    const int lane = (int)threadIdx.x & 63;
    const int wave = (int)threadIdx.x >> 6;
    if (lane == 0) red[wave] = acc;
    __syncthreads();
    if (threadIdx.x == 0) {
        float s = 0.0f;
#pragma unroll
        for (int w = 0; w < TPB / 64; ++w) s += red[w];
        part[blockIdx.y * gridDim.x + blockIdx.x] = s;
    }
}

__global__ __launch_bounds__(256)
void ssim_finalize_kernel(const float* __restrict__ part, int nparts,
                          float* __restrict__ out, float inv_count)
{
    float s = 0.0f;
    for (int i = (int)threadIdx.x; i < nparts; i += 256)
        s += part[i];
#pragma unroll
    for (int off = 32; off > 0; off >>= 1)
        s += __shfl_down(s, off);

    __shared__ float red[4];
    const int lane = (int)threadIdx.x & 63;
    const int wave = (int)threadIdx.x >> 6;
    if (lane == 0) red[wave] = s;
    __syncthreads();
    if (threadIdx.x == 0) {
        float t = red[0] + red[1] + red[2] + red[3];
        out[0] = 1.0f - t * inv_count;
    }
}

extern "C" void kernel_launch(void* const* d_in, const int* in_sizes, int n_in,
                              void* d_out, int out_size, void* d_ws, size_t ws_size,
                              hipStream_t stream)
{
    const float* x = (const float*)d_in[0];
    const float* y = (const float*)d_in[1];
    float* out  = (float*)d_out;
    float* part = (float*)d_ws;   // 4096 floats = 16 KB << ws_size

    const long long total = (long long)in_sizes[0];       // 32*1024*1024
    const int N = (int)(total / ((long long)IMG_H * IMG_W));
    const int nparts = (IMG_H / RPB) * N;

    dim3 grid(IMG_H / RPB, N);
    ssim_map_sum_kernel<<<grid, TPB, 0, stream>>>(x, y, part);

    ssim_finalize_kernel<<<1, 256, 0, stream>>>(part, nparts, out, 1.0f / (float)total);
}